// Round 6
// baseline (215.348 us; speedup 1.0000x reference)
//
#include <hip/hip_runtime.h>
#include <hip/hip_bf16.h>
#include <stdint.h>

// MultiHeadAttention: B=4 S=4096 D=1024 H=16 DH=64; attention is per-token 16x16
// over the head axis. Round 6: A_F32 pipeline restructured — serial window holds
// only {stageB issue, counted vmcnt, 4 ds_write, lgkm}; f32 loads + f2b cvt live
// in the compute region (VALU overlaps MFMA across waves).

namespace {
constexpr int kD  = 1024;
constexpr int kH  = 16;
constexpr int kDH = 64;
constexpr int kM  = 4 * 4096;             // 16384 tokens
constexpr size_t PER = (size_t)kM * kD;   // q/k/v-sized elem count
constexpr size_t WSZ = (size_t)kD * kD;   // weight-sized elem count

typedef __attribute__((ext_vector_type(4))) float f32x4;
typedef __attribute__((ext_vector_type(8))) short s16x8;

__device__ __forceinline__ unsigned short f2b(float f) {
  uint32_t x = __builtin_bit_cast(uint32_t, f);
  x += 0x7fffu + ((x >> 16) & 1u);   // round-to-nearest-even
  return (unsigned short)(x >> 16);
}
__device__ __forceinline__ float b2f(unsigned short u) {
  return __builtin_bit_cast(float, (uint32_t)u << 16);
}

typedef __attribute__((address_space(3))) void as3_void;
typedef __attribute__((address_space(1))) void as1_void;
__device__ __forceinline__ void gload_lds16(const void* g, void* l) {
  // LDS dest is wave-uniform base + lane*16; global src is per-lane.
  __builtin_amdgcn_global_load_lds((const as1_void*)(uintptr_t)g,
                                   (as3_void*)(uint32_t)(uintptr_t)l, 16, 0, 0);
}

// ---------------- weight convert pass: 4 f32 weight matrices -> bf16 ---------
__global__ __launch_bounds__(256) void cvt_w(
    const float* __restrict__ Wq, const float* __restrict__ Wk,
    const float* __restrict__ Wv, const float* __restrict__ Wo,
    unsigned short* __restrict__ out) {
  const size_t total8 = 4 * WSZ / 8;
  for (size_t i8 = (size_t)blockIdx.x * blockDim.x + threadIdx.x; i8 < total8;
       i8 += (size_t)gridDim.x * blockDim.x) {
    size_t i = i8 * 8;
    const float* s; size_t o;
    if (i < WSZ)            { s = Wq; o = i; }
    else if (i < 2 * WSZ)   { s = Wk; o = i - WSZ; }
    else if (i < 3 * WSZ)   { s = Wv; o = i - 2 * WSZ; }
    else                    { s = Wo; o = i - 3 * WSZ; }
    f32x4 f0 = ((const f32x4*)(s + o))[0];
    f32x4 f1 = ((const f32x4*)(s + o))[1];
    s16x8 r;
#pragma unroll
    for (int d = 0; d < 4; ++d) {
      r[d]     = (short)f2b(f0[d]);
      r[4 + d] = (short)f2b(f1[d]);
    }
    *(s16x8*)(out + i) = r;
  }
}

// ---------------- 256x256 GEMM, 2 barriers/K-tile: C[m,n] = sum_k A[m,k]*B[n,k]
// 512 threads = 8 waves (2M x 4N), per-wave output 128x64, BK=64, 2 LDS bufs.
// Loop body = window(t) then compute(t).
//   window(t):  bar(a); stage B(t+1) [+A(t+1) if bf16-A]; counted vmcnt
//               (retires tile-t loads, issued >=1 tile ago -> no stall);
//               [A_F32: ds_write creg(t+1); lgkmcnt(0)]; bar(b).
//   compute(t): [A_F32: issueA(t+2) -> areg]; bw reads; 4 MFMA clusters;
//               [A_F32: after cluster 2, cvt areg->creg (VALU || MFMA)].
// Invariant entering window(t): creg == bf16(A(t+1)); established by prologue.
constexpr int BM2 = 256, BN2 = 256, BK2 = 64;
constexpr int KT2 = kD / BK2;   // 16 K-tiles

template <bool A_F32, bool OUT_F32>
__device__ __forceinline__ void gemm8_body(const void* __restrict__ Ap,
                                           const unsigned short* __restrict__ Bm,
                                           void* __restrict__ Cp) {
  constexpr int N = kD, K = kD;
  __shared__ __align__(16) unsigned short lds[65536];  // 128 KiB: 2 x (A 16K + B 16K elems)

  // T1: XCD-bijective swizzle of the 4x64 = 256-block grid (256 % 8 == 0).
  const int lin = blockIdx.y * gridDim.x + blockIdx.x;   // 0..255
  const int xcd = lin & 7;
  const int idx = lin >> 3;                              // 0..31
  const int m0 = (xcd * 8 + (idx >> 2)) * BM2;
  const int n0 = (idx & 3) * BN2;

  const int t    = threadIdx.x;
  const int lane = t & 63;
  const int w    = t >> 6;        // 0..7
  const int wm   = w >> 2;        // 0..1  (M half)
  const int wn   = w & 3;         // 0..3  (N quarter)

  // B staging (gload_lds): wave w owns rows [w*32, +32), 4 chunks of 8 rows.
  // Linear LDS write (lane*16); global source pre-swizzled (slot ^ row&7).
  const int srow  = lane >> 3;                // 0..7 row within chunk
  const int sslot = (lane & 7) ^ srow;        // pre-swizzled 16B slot
  const unsigned short* gB = Bm + (size_t)(n0 + w * 32 + srow) * K + sslot * 8;
  const unsigned short* gA_b16 =
      A_F32 ? nullptr
            : ((const unsigned short*)Ap + (size_t)(m0 + w * 32 + srow) * K + sslot * 8);
  const float* Af = A_F32 ? (const float*)Ap : nullptr;

  f32x4 acc[8][4];
#pragma unroll
  for (int i = 0; i < 8; ++i)
#pragma unroll
    for (int j = 0; j < 4; ++j) acc[i][j] = (f32x4){0.f, 0.f, 0.f, 0.f};

  const int fr     = lane & 15;
  const int fkslot = lane >> 4;               // 0..3 (16B slot within 64B half)

  f32x4 areg[8];      // in-flight A f32 (A_F32 only)
  s16x8 creg[4];      // converted A bf16, consumed by next window's ds_write

  auto issueA = [&](int k0) {                 // 8 global_load_dwordx4 -> areg
#pragma unroll
    for (int i = 0; i < 4; ++i) {
      const float* src =
          Af + (size_t)(m0 + w * 32 + i * 8 + (lane >> 3)) * K + k0 + (lane & 7) * 8;
      areg[2 * i]     = ((const f32x4*)src)[0];
      areg[2 * i + 1] = ((const f32x4*)src)[1];
    }
  };
  auto cvtA = [&]() {                         // areg -> creg (pure VALU)
#pragma unroll
    for (int i = 0; i < 4; ++i) {
      s16x8 c;
#pragma unroll
      for (int d = 0; d < 4; ++d) {
        c[d]     = (short)f2b(areg[2 * i][d]);
        c[4 + d] = (short)f2b(areg[2 * i + 1][d]);
      }
      creg[i] = c;
    }
  };
  auto dsWriteA = [&](int buf) {              // 4 swizzled ds_write_b128
    const int base = buf * 32768;
#pragma unroll
    for (int i = 0; i < 4; ++i) {
      const int row  = w * 32 + i * 8 + (lane >> 3);
      const int slot = (lane & 7) ^ (row & 7);
      *(s16x8*)(lds + base + row * 64 + slot * 8) = creg[i];
    }
  };
  auto stageA_lds = [&](int buf, int k0) {    // A bf16 via gload_lds
    const int ab = buf * 32768 + w * 2048;
#pragma unroll
    for (int i = 0; i < 4; ++i)
      gload_lds16(gA_b16 + k0 + (size_t)i * 8 * K, lds + ab + i * 512);
  };
  auto stageB = [&](int buf, int k0) {
    const int bb = buf * 32768 + 16384 + w * 2048;
#pragma unroll
    for (int i = 0; i < 4; ++i)
      gload_lds16(gB + k0 + (size_t)i * 8 * K, lds + bb + i * 512);
  };

  auto rdA = [&](int cb, int mi, int kk) -> s16x8 {
    int ra = wm * 128 + mi * 16 + fr;
    int slot = (kk * 4 + fkslot) ^ (ra & 7);
    return *(const s16x8*)(lds + cb + ra * 64 + slot * 8);
  };
  auto rdB = [&](int cb, int nj, int kk) -> s16x8 {
    int rb = wn * 64 + nj * 16 + fr;
    int slot = (kk * 4 + fkslot) ^ (rb & 7);
    return *(const s16x8*)(lds + cb + 16384 + rb * 64 + slot * 8);
  };

  // ---- prologue: tile 0 fully into buf0; creg = bf16(A(1)) ----
  if constexpr (A_F32) {
    issueA(0);                                           // A(0) -> areg
    stageB(0, 0);
    asm volatile("s_waitcnt vmcnt(4)" ::: "memory");     // A(0) landed (B(0) in flight)
    cvtA();
    dsWriteA(0);                                         // A(0) -> buf0
    issueA(BK2);                                         // A(1) -> areg
    asm volatile("s_waitcnt vmcnt(0)" ::: "memory");     // drain B(0) + A(1)
    cvtA();                                              // creg = A(1)
  } else {
    stageA_lds(0, 0);
    stageB(0, 0);
  }

  for (int tt = 0; tt < KT2; ++tt) {
    const int cb = (tt & 1) * 32768;

    // ---------------- window(t) ----------------
    __builtin_amdgcn_s_barrier();   // (a) all waves done reading buf^1 (tile t-1)
    if (tt + 1 < KT2) {
      stageB((tt + 1) & 1, (tt + 1) * BK2);
      if constexpr (!A_F32) {
        stageA_lds((tt + 1) & 1, (tt + 1) * BK2);
        asm volatile("s_waitcnt vmcnt(8)" ::: "memory"); // tile t's 8 loads retired
      } else {
        asm volatile("s_waitcnt vmcnt(4)" ::: "memory"); // B(t) (+older A) retired
      }
    } else {
      asm volatile("s_waitcnt vmcnt(0)" ::: "memory");   // last tile: drain
    }
    if constexpr (A_F32) {
      if (tt + 1 < KT2) dsWriteA((tt + 1) & 1);          // creg = A(t+1) -> buf^1
      asm volatile("s_waitcnt lgkmcnt(0)" ::: "memory"); // ds_writes committed
    }
    __builtin_amdgcn_s_barrier();   // (b) tile t fully visible

    // ---------------- compute(t) ----------------
    if constexpr (A_F32) {
      if (tt + 2 < KT2) issueA((tt + 2) * BK2);          // A(t+2) -> areg (global only)
    }

    s16x8 bw[4][2];
#pragma unroll
    for (int nj = 0; nj < 4; ++nj)
#pragma unroll
      for (int kk = 0; kk < 2; ++kk) bw[nj][kk] = rdB(cb, nj, kk);

#pragma unroll
    for (int q = 0; q < 4; ++q) {
      s16x8 af[2][2];
#pragma unroll
      for (int m2 = 0; m2 < 2; ++m2)
#pragma unroll
        for (int kk = 0; kk < 2; ++kk) af[m2][kk] = rdA(cb, q * 2 + m2, kk);
      __builtin_amdgcn_s_setprio(1);
#pragma unroll
      for (int m2 = 0; m2 < 2; ++m2)
#pragma unroll
        for (int nj = 0; nj < 4; ++nj)
#pragma unroll
          for (int kk = 0; kk < 2; ++kk)
            acc[q * 2 + m2][nj] = __builtin_amdgcn_mfma_f32_16x16x32_bf16(
                af[m2][kk], bw[nj][kk], acc[q * 2 + m2][nj], 0, 0, 0);
      __builtin_amdgcn_s_setprio(0);
      if constexpr (A_F32) {
        if (q == 2 && tt + 2 < KT2) cvtA();   // creg = A(t+2); VALU hides under cluster 3
      }
    }
  }

  // C/D layout: col = lane&15, row = (lane>>4)*4 + r   [verified rounds 1-5]
  const int cr = (lane >> 4) * 4;
  const int cc = lane & 15;
#pragma unroll
  for (int mi = 0; mi < 8; ++mi)
#pragma unroll
    for (int nj = 0; nj < 4; ++nj)
#pragma unroll
      for (int r = 0; r < 4; ++r) {
        size_t row = (size_t)(m0 + wm * 128 + mi * 16 + cr + r);
        size_t col = (size_t)(n0 + wn * 64 + nj * 16 + cc);
        if constexpr (OUT_F32)
          ((float*)Cp)[row * N + col] = acc[mi][nj][r];
        else
          ((unsigned short*)Cp)[row * N + col] = f2b(acc[mi][nj][r]);
      }
}

__global__ __launch_bounds__(512, 2) void proj_gemm8(
    const float* __restrict__ q, const float* __restrict__ k, const float* __restrict__ v,
    const unsigned short* __restrict__ Wqb, const unsigned short* __restrict__ Wkb,
    const unsigned short* __restrict__ Wvb, unsigned short* __restrict__ qh,
    unsigned short* __restrict__ kh, unsigned short* __restrict__ vh) {
  const float* A;
  const unsigned short* W;
  unsigned short* C;
  if (blockIdx.z == 0)      { A = q; W = Wqb; C = qh; }
  else if (blockIdx.z == 1) { A = k; W = Wkb; C = kh; }
  else                      { A = v; W = Wvb; C = vh; }
  gemm8_body<true, false>(A, W, C);
}

__global__ __launch_bounds__(512, 2) void out_gemm8(const unsigned short* __restrict__ attn,
                                                    const unsigned short* __restrict__ Wob,
                                                    float* __restrict__ out) {
  gemm8_body<false, true>(attn, Wob, out);
}

// ---------------- per-token head-axis attention (verified rounds 1-5) --------
__global__ __launch_bounds__(256) void attn_tok(const unsigned short* __restrict__ qh,
                                                const unsigned short* __restrict__ kh,
                                                const unsigned short* __restrict__ vh,
                                                const float* __restrict__ mask,
                                                unsigned short* __restrict__ attn) {
  __shared__ float P[4][16][17];
  __shared__ __align__(16) unsigned short Vs[4][16 * 64];
  const int lane = threadIdx.x & 63;
  const int wid  = threadIdx.x >> 6;
  const size_t tok = (size_t)blockIdx.x * 4 + wid;

  const unsigned short* qp = qh + tok * kD;
  const unsigned short* kp = kh + tok * kD;
  const unsigned short* vp = vh + tok * kD;

  {
    const s16x8* src = (const s16x8*)vp;
    s16x8 a = src[2 * lane], b = src[2 * lane + 1];
    s16x8* dst = (s16x8*)Vs[wid];
    dst[2 * lane] = a;
    dst[2 * lane + 1] = b;
  }

  const int fr = lane & 15;
  const int fk = (lane >> 4) * 8;
  s16x8 a0 = *(const s16x8*)(qp + fr * kDH + fk);
  s16x8 a1 = *(const s16x8*)(qp + fr * kDH + 32 + fk);
  s16x8 b0 = *(const s16x8*)(kp + fr * kDH + fk);
  s16x8 b1 = *(const s16x8*)(kp + fr * kDH + 32 + fk);
  f32x4 s = {0.f, 0.f, 0.f, 0.f};
  s = __builtin_amdgcn_mfma_f32_16x16x32_bf16(a0, b0, s, 0, 0, 0);
  s = __builtin_amdgcn_mfma_f32_16x16x32_bf16(a1, b1, s, 0, 0, 0);

  const int cr = (lane >> 4) * 4;
  const int cc = lane & 15;
  float p[4];
#pragma unroll
  for (int r = 0; r < 4; ++r) {
    float val = s[r] * 0.125f * mask[(cr + r) * kH + cc];
    float mx = val;
#pragma unroll
    for (int d = 1; d < 16; d <<= 1) mx = fmaxf(mx, __shfl_xor(mx, d));
    float e = __expf(val - mx);
    float sum = e;
#pragma unroll
    for (int d = 1; d < 16; d <<= 1) sum += __shfl_xor(sum, d);
    p[r] = e / sum;
  }
#pragma unroll
  for (int r = 0; r < 4; ++r) P[wid][cr + r][cc] = p[r];

  const int h  = lane >> 2;
  const int d0 = (lane & 3) * 16;
  float o[16];
#pragma unroll
  for (int i = 0; i < 16; ++i) o[i] = 0.f;
#pragma unroll
  for (int g = 0; g < 16; ++g) {
    float pg = P[wid][h][g];
    s16x8 v0 = *(const s16x8*)(Vs[wid] + g * kDH + d0);
    s16x8 v1 = *(const s16x8*)(Vs[wid] + g * kDH + d0 + 8);
#pragma unroll
    for (int dd = 0; dd < 8; ++dd) {
      o[dd]     += pg * b2f((unsigned short)v0[dd]);
      o[8 + dd] += pg * b2f((unsigned short)v1[dd]);
    }
  }
  unsigned short* op = attn + tok * kD + h * kDH + d0;
  s16x8 r0, r1;
#pragma unroll
  for (int dd = 0; dd < 8; ++dd) {
    r0[dd] = (short)f2b(o[dd]);
    r1[dd] = (short)f2b(o[dd + 8]);
  }
  *(s16x8*)op = r0;
  *(s16x8*)(op + 8) = r1;
}

// ---------------- fallback (round-1 verified path, fused-cvt GEMM) ----------
constexpr int BM = 128, BN = 128, BK = 32;
constexpr int LDSP = BK + 8;
__device__ __forceinline__ void cvt16_store(const float* __restrict__ g, short* __restrict__ l) {
  const f32x4* s4 = (const f32x4*)g;
  f32x4 f0 = s4[0], f1 = s4[1], f2 = s4[2], f3 = s4[3];
  s16x8 o0, o1;
#pragma unroll
  for (int i = 0; i < 4; ++i) {
    o0[i]     = (short)f2b(f0[i]);
    o0[4 + i] = (short)f2b(f1[i]);
    o1[i]     = (short)f2b(f2[i]);
    o1[4 + i] = (short)f2b(f3[i]);
  }
  *(s16x8*)l = o0;
  *(s16x8*)(l + 8) = o1;
}

template <bool A_BF16, bool OUT_F32>
__device__ __forceinline__ void gemm_body_cvt(const void* __restrict__ Ap,
                                              const float* __restrict__ Wp,
                                              void* __restrict__ Cp) {
  constexpr int N = kD, K = kD;
  __shared__ short As[BM * LDSP];
  __shared__ short Bs[BN * LDSP];
  const int t  = threadIdx.x;
  const int m0 = blockIdx.y * BM;
  const int n0 = blockIdx.x * BN;
  const int srow = t >> 1;
  const int scol = (t & 1) * 16;
  const int lane = t & 63;
  const int wid  = t >> 6;
  const int wm   = (wid >> 1) * 64;
  const int wn   = (wid & 1) * 64;
  const int fr   = lane & 15;
  const int fk   = (lane >> 4) * 8;

  f32x4 acc[4][4];
#pragma unroll
  for (int i = 0; i < 4; ++i)
#pragma unroll
    for (int j = 0; j < 4; ++j) acc[i][j] = (f32x4){0.f, 0.f, 0.f, 0.f};

  for (int k0 = 0; k0 < K; k0 += BK) {
    if constexpr (A_BF16) {
      const unsigned short* Ab = (const unsigned short*)Ap;
      const s16x8* src = (const s16x8*)(Ab + (size_t)(m0 + srow) * K + k0 + scol);
      s16x8 v0 = src[0], v1 = src[1];
      *(s16x8*)(As + srow * LDSP + scol) = v0;
      *(s16x8*)(As + srow * LDSP + scol + 8) = v1;
    } else {
      cvt16_store((const float*)Ap + (size_t)(m0 + srow) * K + k0 + scol,
                  As + srow * LDSP + scol);
    }
    cvt16_store(Wp + (size_t)(n0 + srow) * K + k0 + scol, Bs + srow * LDSP + scol);
    __syncthreads();
    s16x8 af[4], bw[4];
#pragma unroll
    for (int i = 0; i < 4; ++i)
      af[i] = *(const s16x8*)(As + (wm + i * 16 + fr) * LDSP + fk);
#pragma unroll
    for (int j = 0; j < 4; ++j)
      bw[j] = *(const s16x8*)(Bs + (wn + j * 16 + fr) * LDSP + fk);
#pragma unroll
    for (int i = 0; i < 4; ++i)
#pragma unroll
      for (int j = 0; j < 4; ++j)
        acc[i][j] = __builtin_amdgcn_mfma_f32_16x16x32_bf16(af[i], bw[j], acc[i][j], 0, 0, 0);
    __syncthreads();
  }
  const int cr = (lane >> 4) * 4;
  const int cc = lane & 15;
#pragma unroll
  for (int i = 0; i < 4; ++i)
#pragma unroll
    for (int j = 0; j < 4; ++j)
#pragma unroll
      for (int r = 0; r < 4; ++r) {
        size_t row = (size_t)(m0 + wm + i * 16 + cr + r);
        size_t col = (size_t)(n0 + wn + j * 16 + cc);
        if constexpr (OUT_F32)
          ((float*)Cp)[row * N + col] = acc[i][j][r];
        else
          ((unsigned short*)Cp)[row * N + col] = f2b(acc[i][j][r]);
      }
}

__global__ __launch_bounds__(256) void proj_gemm_cvt(
    const float* __restrict__ q, const float* __restrict__ k, const float* __restrict__ v,
    const float* __restrict__ Wq, const float* __restrict__ Wk, const float* __restrict__ Wv,
    unsigned short* __restrict__ qh, unsigned short* __restrict__ kh,
    unsigned short* __restrict__ vh) {
  const float* A; const float* W; unsigned short* C;
  if (blockIdx.z == 0)      { A = q; W = Wq; C = qh; }
  else if (blockIdx.z == 1) { A = k; W = Wk; C = kh; }
  else                      { A = v; W = Wv; C = vh; }
  gemm_body_cvt<false, false>(A, W, C);
}

__global__ __launch_bounds__(256) void out_gemm_cvt(const unsigned short* __restrict__ attn,
                                                    const float* __restrict__ Wo,
                                                    float* __restrict__ out) {
  gemm_body_cvt<true, true>(attn, Wo, out);
}

}  // namespace

extern "C" void kernel_launch(void* const* d_in, const int* in_sizes, int n_in,
                              void* d_out, int out_size, void* d_ws, size_t ws_size,
                              hipStream_t stream) {
  (void)in_sizes; (void)n_in; (void)out_size;
  const float* q    = (const float*)d_in[0];
  const float* k    = (const float*)d_in[1];
  const float* v    = (const float*)d_in[2];
  const float* mask = (const float*)d_in[3];
  const float* Wq   = (const float*)d_in[4];
  const float* Wk   = (const float*)d_in[5];
  const float* Wv   = (const float*)d_in[6];
  const float* Wo   = (const float*)d_in[7];

  const size_t need = (3 * PER + 4 * WSZ) * sizeof(unsigned short);  // ~109 MB
  if (ws_size >= need) {
    unsigned short* Wqb = (unsigned short*)d_ws;   // ws: Wq Wk Wv Wo | qh kh vh
    unsigned short* Wkb = Wqb + WSZ;
    unsigned short* Wvb = Wkb + WSZ;
    unsigned short* Wob = Wvb + WSZ;
    unsigned short* qh  = Wob + WSZ;
    unsigned short* kh  = qh + PER;
    unsigned short* vh  = kh + PER;
    // at aliases qh: attn wave reads token t's q-row before writing its attn
    // row (same wave, read-before-write, rows disjoint across tokens).
    unsigned short* at  = qh;

    cvt_w<<<256, 256, 0, stream>>>(Wq, Wk, Wv, Wo, Wqb);
    proj_gemm8<<<dim3(kD / BN2, kM / BM2, 3), 512, 0, stream>>>(q, k, v, Wqb, Wkb, Wvb,
                                                                qh, kh, vh);
    attn_tok<<<dim3(kM / 4), 256, 0, stream>>>(qh, kh, vh, mask, at);
    out_gemm8<<<dim3(kD / BN2, kM / BM2), 512, 0, stream>>>(at, Wob, (float*)d_out);
  } else {
    // round-1 verified fallback (fused-convert GEMMs)
    unsigned short* qh = (unsigned short*)d_ws;
    unsigned short* kh = qh + PER;
    unsigned short* vh = kh + PER;
    unsigned short* at = (ws_size >= 4 * PER * sizeof(unsigned short)) ? (vh + PER) : qh;
    proj_gemm_cvt<<<dim3(kD / BN, kM / BM, 3), 256, 0, stream>>>(q, k, v, Wq, Wk, Wv,
                                                                 qh, kh, vh);
    attn_tok<<<dim3(kM / 4), 256, 0, stream>>>(qh, kh, vh, mask, at);
    out_gemm_cvt<<<dim3(kD / BN, kM / BM), 256, 0, stream>>>(at, Wo, (float*)d_out);
  }
}